// Round 6
// baseline (81.520 us; speedup 1.0000x reference)
//
#include <hip/hip_runtime.h>
#include <math.h>

#define B 32
#define C 4
#define CF 5
#define WPB 16          // waves per block; each wave handles one l
#define NTHR (WPB * 64)

// Fully fused: per-block w-table, per-lane row ownership in registers,
// all-pairs JS via 8 shfl rotation steps, CE + R2 inline, block partials,
// last-block final reduction + epilogue (counter zeroed by memset each call).
__global__ __launch_bounds__(NTHR) void k_all(const float* __restrict__ logits,
                                              const float* __restrict__ prob,
                                              const float* __restrict__ y_true,
                                              const float* __restrict__ yevo,
                                              float* __restrict__ partials,
                                              unsigned* __restrict__ counter,
                                              float* __restrict__ out,
                                              int L, int nblk) {
    const int t = threadIdx.x;
    const int lane = t & 63;
    const int g = lane >> 5;            // 0: d=1..8 (+CE/R2), 1: d=9..16
    const int b = lane & 31;            // owned batch row
    const int wv = t >> 6;              // wave id in block
    const int l = (blockIdx.x << 4) | wv;

    __shared__ float w[1024];
    __shared__ float wred[WPB][5];
    __shared__ unsigned done_s;

    // ---- hoisted global loads (overlap with w-table compute) ----
    const float* yt = y_true + ((size_t)b * L + l) * CF;
    float y0 = yt[0], y1 = yt[1], y2 = yt[2], y3 = yt[3], y4 = yt[4];
    float4 pv = *(const float4*)(prob + ((size_t)b * L + l) * C);
    float4 av = make_float4(0.f, 0.f, 0.f, 0.f);
    if (g == 0) av = *(const float4*)(logits + ((size_t)b * L + l) * C);
    float ew = __expf(-2.0f * yevo[t]);

    // ---- phase 0: w[i][j] = exp(-2y)/(rowsum+eps); one element/thread ----
    {
        float s = ew;
        s += __shfl_xor(s, 1);
        s += __shfl_xor(s, 2);
        s += __shfl_xor(s, 4);
        s += __shfl_xor(s, 8);
        s += __shfl_xor(s, 16);         // rowsum over 32 lanes (i = t>>5)
        w[t] = ew / (s + 1e-8f);
    }

    // ---- phase 1: label/CE/R2 from registers ----
    float ce = 0.f, valid = 0.f, r2s = 0.f, tv = 0.f;

    int lbl = 0; float best = y0;
    if (y1 > best) { best = y1; lbl = 1; }
    if (y2 > best) { best = y2; lbl = 2; }
    if (y3 > best) { best = y3; lbl = 3; }
    if (y4 > best) { best = y4; lbl = 4; }
    float salt = y1 + y2 + y3;

    float spalt = pv.y + pv.z + pv.w;           // raw probs per reference
    float q0 = fmaxf(pv.x, 1e-7f), q1 = fmaxf(pv.y, 1e-7f);
    float q2 = fmaxf(pv.z, 1e-7f), q3 = fmaxf(pv.w, 1e-7f);
    float plp = q0 * __logf(q0) + q1 * __logf(q1)
              + q2 * __logf(q2) + q3 * __logf(q3);

    if (g == 0) {
        if (lbl != 4) {
            float mx = fmaxf(fmaxf(av.x, av.y), fmaxf(av.z, av.w));
            float se = __expf(av.x - mx) + __expf(av.y - mx)
                     + __expf(av.z - mx) + __expf(av.w - mx);
            float lse = mx + __logf(se);
            float al = (lbl == 0) ? av.x : (lbl == 1) ? av.y
                     : (lbl == 2) ? av.z : av.w;
            ce = lse - al;
            valid = 1.f;
        }
        // R2: groups of 4 = b bits 0,1 (= lane bits 0,1; stays in g0 half)
        float nmc = (lbl != 4) ? 1.f : 0.f, altc = salt, ps = spalt;
        nmc  += __shfl_xor(nmc, 1);   nmc  += __shfl_xor(nmc, 2);
        altc += __shfl_xor(altc, 1);  altc += __shfl_xor(altc, 2);
        ps   += __shfl_xor(ps, 1);    ps   += __shfl_xor(ps, 2);
        float af = altc / fmaxf(nmc, 1.f);
        float pred = 0.25f * ps;
        bool miss = (lbl == 4);
        float taf = miss ? 0.5f : af;
        bool edge = (taf == 0.f) || (taf == 1.f);
        float denom = fmaxf(taf * (1.f - taf), 0.01f);
        float d = pred - taf;
        float r2 = d * d / denom;
        if (edge || miss) r2 = 0.f;
        r2s -= r2;
        if (nmc > 0.f && r2 != 0.f) tv += 1.f;
    }

    __syncthreads();                    // w table ready

    // ---- phase 2: 8 rotation steps; half-wave g covers d = 1+8g .. 8+8g ----
    float evo = 0.f;
    #pragma unroll
    for (int it = 0; it < 8; ++it) {
        int d = 1 + it + (g << 3);
        int jj = (b + d) & 31;
        int src = (lane & 32) | jj;
        float qj0 = __shfl(q0, src), qj1 = __shfl(q1, src);
        float qj2 = __shfl(q2, src), qj3 = __shfl(q3, src);
        float pj  = __shfl(plp, src);
        int   lj  = __shfl(lbl, src);
        float m0 = 0.5f * (q0 + qj0), m1 = 0.5f * (q1 + qj1);
        float m2 = 0.5f * (q2 + qj2), m3 = 0.5f * (q3 + qj3);
        float mlogm = m0 * __logf(m0) + m1 * __logf(m1)
                    + m2 * __logf(m2) + m3 * __logf(m3);
        float js = 0.5f * (plp + pj) - mlogm;
        bool act = (lbl == lj) && (lbl != 4) && !((d == 16) & (b >= 16));
        float wf = act ? (w[(b << 5) + jj] + w[(jj << 5) + b]) : 0.f;
        evo = fmaf(wf, js, evo);
    }

    // ---- wave reduction of 5 accumulators ----
    #pragma unroll
    for (int off = 32; off; off >>= 1) {
        ce += __shfl_xor(ce, off);   valid += __shfl_xor(valid, off);
        r2s += __shfl_xor(r2s, off); tv += __shfl_xor(tv, off);
        evo += __shfl_xor(evo, off);
    }
    if (lane == 0) {
        wred[wv][0] = ce; wred[wv][1] = valid; wred[wv][2] = r2s;
        wred[wv][3] = tv; wred[wv][4] = evo;
    }
    __syncthreads();

    // ---- cross-wave reduction (16 waves) by wave 0, lanes 0..15 ----
    if (t < 16) {
        float a0 = wred[t][0], a1 = wred[t][1], a2 = wred[t][2],
              a3 = wred[t][3], a4 = wred[t][4];
        #pragma unroll
        for (int off = 8; off; off >>= 1) {
            a0 += __shfl_xor(a0, off); a1 += __shfl_xor(a1, off);
            a2 += __shfl_xor(a2, off); a3 += __shfl_xor(a3, off);
            a4 += __shfl_xor(a4, off);
        }
        if (t == 0) {
            float* p = partials + (size_t)blockIdx.x * 8;
            p[0] = a0; p[1] = a1; p[2] = a2; p[3] = a3; p[4] = a4;
        }
    }

    // ---- last-block-done tail: final reduction + epilogue ----
    __threadfence();                         // release this block's partials
    if (t == 0) done_s = atomicAdd(counter, 1u);
    __syncthreads();
    if (done_s != (unsigned)(nblk - 1)) return;
    __threadfence();                         // acquire all partials

    float s0 = 0.f, s1 = 0.f, s2 = 0.f, s3 = 0.f, s4 = 0.f;
    if (t < nblk) {                          // nblk = 256 <= NTHR
        const float* p = partials + (size_t)t * 8;
        s0 = p[0]; s1 = p[1]; s2 = p[2]; s3 = p[3]; s4 = p[4];
    }
    #pragma unroll
    for (int off = 32; off; off >>= 1) {
        s0 += __shfl_xor(s0, off); s1 += __shfl_xor(s1, off);
        s2 += __shfl_xor(s2, off); s3 += __shfl_xor(s3, off);
        s4 += __shfl_xor(s4, off);
    }
    if (lane == 0) {
        wred[wv][0] = s0; wred[wv][1] = s1; wred[wv][2] = s2;
        wred[wv][3] = s3; wred[wv][4] = s4;
    }
    __syncthreads();
    if (t == 0) {
        float ce_sum = 0.f, vcnt = 0.f, r2_sum = 0.f, tvs = 0.f, evo_s = 0.f;
        #pragma unroll
        for (int k = 0; k < 4; ++k) {        // only waves 0..3 held data
            ce_sum += wred[k][0]; vcnt += wred[k][1]; r2_sum += wred[k][2];
            tvs += wred[k][3]; evo_s += wred[k][4];
        }
        float ce_loss = (vcnt > 0.f) ? (ce_sum / fmaxf(vcnt, 1.f)) : ce_sum;
        float r2_loss = 0.1f * ((tvs > 0.f) ? (r2_sum / fmaxf(tvs, 1.f)) : r2_sum);
        float evo = 10.f * (evo_s / 32.f);
        if (!isfinite(evo)) evo = 0.f;
        out[0] = 1000.f * (ce_loss + r2_loss + evo);
    }
}

extern "C" void kernel_launch(void* const* d_in, const int* in_sizes, int n_in,
                              void* d_out, int out_size, void* d_ws, size_t ws_size,
                              hipStream_t stream) {
    const float* logits = (const float*)d_in[0];
    const float* prob   = (const float*)d_in[1];
    const float* y_true = (const float*)d_in[2];
    const float* yevo   = (const float*)d_in[3];
    float* out = (float*)d_out;

    const int L = in_sizes[0] / (B * C);   // 4096
    const int nblk = L / WPB;              // 256

    float* partials   = (float*)d_ws;                       // nblk*8 floats
    unsigned* counter = (unsigned*)((float*)d_ws + 8 * nblk);

    hipMemsetAsync(counter, 0, sizeof(unsigned), stream);
    k_all<<<nblk, NTHR, 0, stream>>>(logits, prob, y_true, yevo,
                                     partials, counter, out, L, nblk);
}

// Round 7
// 22.721 us; speedup vs baseline: 3.5879x; 3.5879x over previous
//
#include <hip/hip_runtime.h>
#include <math.h>

#define B 32
#define C 4
#define CF 5
#define WPB 16          // waves per block; each wave handles one l
#define NTHR (WPB * 64)

// Fully fused, fence-free tail: per-block w-table, per-lane row ownership,
// all-pairs JS via 8 shfl rotation steps, CE + R2 inline; block partials
// published with agent-scope coherent stores (sc1), counter via relaxed
// agent atomic, last block reduces with agent-scope loads. NO __threadfence
// (device fence = full L2 writeback across 8 XCDs = ~75us, measured R6).
__global__ __launch_bounds__(NTHR) void k_all(const float* __restrict__ logits,
                                              const float* __restrict__ prob,
                                              const float* __restrict__ y_true,
                                              const float* __restrict__ yevo,
                                              float* __restrict__ partials,
                                              unsigned* __restrict__ counter,
                                              float* __restrict__ out,
                                              int L, int nblk) {
    const int t = threadIdx.x;
    const int lane = t & 63;
    const int g = lane >> 5;            // 0: d=1..8 (+CE/R2), 1: d=9..16
    const int b = lane & 31;            // owned batch row
    const int wv = t >> 6;              // wave id in block
    const int l = (blockIdx.x << 4) | wv;

    __shared__ float w[1024];
    __shared__ float wred[WPB][5];
    __shared__ unsigned done_s;

    // ---- hoisted global loads (overlap with w-table compute) ----
    const float* yt = y_true + ((size_t)b * L + l) * CF;
    float y0 = yt[0], y1 = yt[1], y2 = yt[2], y3 = yt[3], y4 = yt[4];
    float4 pv = *(const float4*)(prob + ((size_t)b * L + l) * C);
    float4 av = make_float4(0.f, 0.f, 0.f, 0.f);
    if (g == 0) av = *(const float4*)(logits + ((size_t)b * L + l) * C);
    float ew = __expf(-2.0f * yevo[t]);

    // ---- phase 0: w[i][j] = exp(-2y)/(rowsum+eps); one element/thread ----
    {
        float s = ew;
        s += __shfl_xor(s, 1);
        s += __shfl_xor(s, 2);
        s += __shfl_xor(s, 4);
        s += __shfl_xor(s, 8);
        s += __shfl_xor(s, 16);         // rowsum over 32 lanes (i = t>>5)
        w[t] = ew / (s + 1e-8f);
    }

    // ---- phase 1: label/CE/R2 from registers ----
    float ce = 0.f, valid = 0.f, r2s = 0.f, tv = 0.f;

    int lbl = 0; float best = y0;
    if (y1 > best) { best = y1; lbl = 1; }
    if (y2 > best) { best = y2; lbl = 2; }
    if (y3 > best) { best = y3; lbl = 3; }
    if (y4 > best) { best = y4; lbl = 4; }
    float salt = y1 + y2 + y3;

    float spalt = pv.y + pv.z + pv.w;           // raw probs per reference
    float q0 = fmaxf(pv.x, 1e-7f), q1 = fmaxf(pv.y, 1e-7f);
    float q2 = fmaxf(pv.z, 1e-7f), q3 = fmaxf(pv.w, 1e-7f);
    float plp = q0 * __logf(q0) + q1 * __logf(q1)
              + q2 * __logf(q2) + q3 * __logf(q3);

    if (g == 0) {
        if (lbl != 4) {
            float mx = fmaxf(fmaxf(av.x, av.y), fmaxf(av.z, av.w));
            float se = __expf(av.x - mx) + __expf(av.y - mx)
                     + __expf(av.z - mx) + __expf(av.w - mx);
            float lse = mx + __logf(se);
            float al = (lbl == 0) ? av.x : (lbl == 1) ? av.y
                     : (lbl == 2) ? av.z : av.w;
            ce = lse - al;
            valid = 1.f;
        }
        // R2: groups of 4 = b bits 0,1 (= lane bits 0,1; stays in g0 half)
        float nmc = (lbl != 4) ? 1.f : 0.f, altc = salt, ps = spalt;
        nmc  += __shfl_xor(nmc, 1);   nmc  += __shfl_xor(nmc, 2);
        altc += __shfl_xor(altc, 1);  altc += __shfl_xor(altc, 2);
        ps   += __shfl_xor(ps, 1);    ps   += __shfl_xor(ps, 2);
        float af = altc / fmaxf(nmc, 1.f);
        float pred = 0.25f * ps;
        bool miss = (lbl == 4);
        float taf = miss ? 0.5f : af;
        bool edge = (taf == 0.f) || (taf == 1.f);
        float denom = fmaxf(taf * (1.f - taf), 0.01f);
        float d = pred - taf;
        float r2 = d * d / denom;
        if (edge || miss) r2 = 0.f;
        r2s -= r2;
        if (nmc > 0.f && r2 != 0.f) tv += 1.f;
    }

    __syncthreads();                    // w table ready

    // ---- phase 2: 8 rotation steps; half-wave g covers d = 1+8g .. 8+8g ----
    float evo = 0.f;
    #pragma unroll
    for (int it = 0; it < 8; ++it) {
        int d = 1 + it + (g << 3);
        int jj = (b + d) & 31;
        int src = (lane & 32) | jj;
        float qj0 = __shfl(q0, src), qj1 = __shfl(q1, src);
        float qj2 = __shfl(q2, src), qj3 = __shfl(q3, src);
        float pj  = __shfl(plp, src);
        int   lj  = __shfl(lbl, src);
        float m0 = 0.5f * (q0 + qj0), m1 = 0.5f * (q1 + qj1);
        float m2 = 0.5f * (q2 + qj2), m3 = 0.5f * (q3 + qj3);
        float mlogm = m0 * __logf(m0) + m1 * __logf(m1)
                    + m2 * __logf(m2) + m3 * __logf(m3);
        float js = 0.5f * (plp + pj) - mlogm;
        bool act = (lbl == lj) && (lbl != 4) && !((d == 16) & (b >= 16));
        float wf = act ? (w[(b << 5) + jj] + w[(jj << 5) + b]) : 0.f;
        evo = fmaf(wf, js, evo);
    }

    // ---- wave reduction of 5 accumulators ----
    #pragma unroll
    for (int off = 32; off; off >>= 1) {
        ce += __shfl_xor(ce, off);   valid += __shfl_xor(valid, off);
        r2s += __shfl_xor(r2s, off); tv += __shfl_xor(tv, off);
        evo += __shfl_xor(evo, off);
    }
    if (lane == 0) {
        wred[wv][0] = ce; wred[wv][1] = valid; wred[wv][2] = r2s;
        wred[wv][3] = tv; wred[wv][4] = evo;
    }
    __syncthreads();

    // ---- cross-wave reduction (16 waves) by wave 0, lanes 0..15 ----
    if (t < 16) {
        float a0 = wred[t][0], a1 = wred[t][1], a2 = wred[t][2],
              a3 = wred[t][3], a4 = wred[t][4];
        #pragma unroll
        for (int off = 8; off; off >>= 1) {
            a0 += __shfl_xor(a0, off); a1 += __shfl_xor(a1, off);
            a2 += __shfl_xor(a2, off); a3 += __shfl_xor(a3, off);
            a4 += __shfl_xor(a4, off);
        }
        if (t == 0) {
            float* p = partials + (size_t)blockIdx.x * 8;
            // agent-scope coherent stores (global_store ... sc1): visible
            // device-wide without any L2 writeback instruction.
            __hip_atomic_store(&p[0], a0, __ATOMIC_RELAXED, __HIP_MEMORY_SCOPE_AGENT);
            __hip_atomic_store(&p[1], a1, __ATOMIC_RELAXED, __HIP_MEMORY_SCOPE_AGENT);
            __hip_atomic_store(&p[2], a2, __ATOMIC_RELAXED, __HIP_MEMORY_SCOPE_AGENT);
            __hip_atomic_store(&p[3], a3, __ATOMIC_RELAXED, __HIP_MEMORY_SCOPE_AGENT);
            __hip_atomic_store(&p[4], a4, __ATOMIC_RELAXED, __HIP_MEMORY_SCOPE_AGENT);
            // ensure the 5 stores reached the coherent point, then signal
            asm volatile("s_waitcnt vmcnt(0)" ::: "memory");
            done_s = __hip_atomic_fetch_add(counter, 1u, __ATOMIC_RELAXED,
                                            __HIP_MEMORY_SCOPE_AGENT);
        }
    }
    __syncthreads();
    if (done_s != (unsigned)(nblk - 1)) return;

    // ---- last block: final reduction + epilogue (agent-scope loads) ----
    float s0 = 0.f, s1 = 0.f, s2 = 0.f, s3 = 0.f, s4 = 0.f;
    if (t < nblk) {                          // nblk = 256 <= NTHR
        const float* p = partials + (size_t)t * 8;
        s0 = __hip_atomic_load(&p[0], __ATOMIC_RELAXED, __HIP_MEMORY_SCOPE_AGENT);
        s1 = __hip_atomic_load(&p[1], __ATOMIC_RELAXED, __HIP_MEMORY_SCOPE_AGENT);
        s2 = __hip_atomic_load(&p[2], __ATOMIC_RELAXED, __HIP_MEMORY_SCOPE_AGENT);
        s3 = __hip_atomic_load(&p[3], __ATOMIC_RELAXED, __HIP_MEMORY_SCOPE_AGENT);
        s4 = __hip_atomic_load(&p[4], __ATOMIC_RELAXED, __HIP_MEMORY_SCOPE_AGENT);
    }
    #pragma unroll
    for (int off = 32; off; off >>= 1) {
        s0 += __shfl_xor(s0, off); s1 += __shfl_xor(s1, off);
        s2 += __shfl_xor(s2, off); s3 += __shfl_xor(s3, off);
        s4 += __shfl_xor(s4, off);
    }
    if (lane == 0 && t < 256) {
        wred[wv][0] = s0; wred[wv][1] = s1; wred[wv][2] = s2;
        wred[wv][3] = s3; wred[wv][4] = s4;
    }
    __syncthreads();
    if (t == 0) {
        float ce_sum = 0.f, vcnt = 0.f, r2_sum = 0.f, tvs = 0.f, evo_s = 0.f;
        #pragma unroll
        for (int k = 0; k < 4; ++k) {        // waves 0..3 held data
            ce_sum += wred[k][0]; vcnt += wred[k][1]; r2_sum += wred[k][2];
            tvs += wred[k][3]; evo_s += wred[k][4];
        }
        float ce_loss = (vcnt > 0.f) ? (ce_sum / fmaxf(vcnt, 1.f)) : ce_sum;
        float r2_loss = 0.1f * ((tvs > 0.f) ? (r2_sum / fmaxf(tvs, 1.f)) : r2_sum);
        float evo = 10.f * (evo_s / 32.f);
        if (!isfinite(evo)) evo = 0.f;
        out[0] = 1000.f * (ce_loss + r2_loss + evo);
    }
}

extern "C" void kernel_launch(void* const* d_in, const int* in_sizes, int n_in,
                              void* d_out, int out_size, void* d_ws, size_t ws_size,
                              hipStream_t stream) {
    const float* logits = (const float*)d_in[0];
    const float* prob   = (const float*)d_in[1];
    const float* y_true = (const float*)d_in[2];
    const float* yevo   = (const float*)d_in[3];
    float* out = (float*)d_out;

    const int L = in_sizes[0] / (B * C);   // 4096
    const int nblk = L / WPB;              // 256

    float* partials   = (float*)d_ws;                       // nblk*8 floats
    unsigned* counter = (unsigned*)((float*)d_ws + 8 * nblk);

    hipMemsetAsync(counter, 0, sizeof(unsigned), stream);
    k_all<<<nblk, NTHR, 0, stream>>>(logits, prob, y_true, yevo,
                                     partials, counter, out, L, nblk);
}

// Round 8
// 14.699 us; speedup vs baseline: 5.5461x; 1.5458x over previous
//
#include <hip/hip_runtime.h>
#include <math.h>

#define B 32
#define C 4
#define CF 5
#define WPB 16          // waves per block; wave wv handles l = blk*16 + wv
#define NTHR (WPB * 64) // 1024

// k_main: record-parallel coalesced staging (threads 0..511, one (b,l) record
// each) + w-table build (threads 512..1023), then per-wave all-pairs JS via
// 8 in-register shfl rotation steps. Two-kernel shape (R5 champion skeleton).
__global__ __launch_bounds__(NTHR) void k_main(const float* __restrict__ logits,
                                               const float* __restrict__ prob,
                                               const float* __restrict__ y_true,
                                               const float* __restrict__ yevo,
                                               float* __restrict__ partials,
                                               int L, int nblk) {
    const int t = threadIdx.x;
    const int blk = blockIdx.x;
    const int l0 = blk << 4;

    __shared__ float w[1024];                   // evo weight matrix
    __shared__ float sq0[WPB][33], sq1[WPB][33], sq2[WPB][33], sq3[WPB][33];
    __shared__ float sm[WPB][33];               // sum p*log p
    __shared__ int   sl[WPB][33];               // labels
    __shared__ float wred[WPB][5];

    float ce = 0.f, valid = 0.f, r2s = 0.f, tv = 0.f;

    if (t < 512) {
        // ---- one (b, l) record per thread; consecutive t -> consecutive l
        //      => contiguous 256-320 B global segments (coalesced) ----
        const int b = t >> 4, ll = t & 15;
        const int l = l0 + ll;
        const float* yt = y_true + ((size_t)b * L + l) * CF;
        float y0 = yt[0], y1 = yt[1], y2 = yt[2], y3 = yt[3], y4 = yt[4];
        float4 pv = *(const float4*)(prob + ((size_t)b * L + l) * C);
        float4 av = *(const float4*)(logits + ((size_t)b * L + l) * C);

        int lbl = 0; float best = y0;
        if (y1 > best) { best = y1; lbl = 1; }
        if (y2 > best) { best = y2; lbl = 2; }
        if (y3 > best) { best = y3; lbl = 3; }
        if (y4 > best) { best = y4; lbl = 4; }
        float salt = y1 + y2 + y3;

        float spalt = pv.y + pv.z + pv.w;       // raw probs per reference
        float q0 = fmaxf(pv.x, 1e-7f), q1 = fmaxf(pv.y, 1e-7f);
        float q2 = fmaxf(pv.z, 1e-7f), q3 = fmaxf(pv.w, 1e-7f);
        float plp = q0 * __logf(q0) + q1 * __logf(q1)
                  + q2 * __logf(q2) + q3 * __logf(q3);

        sq0[ll][b] = q0; sq1[ll][b] = q1; sq2[ll][b] = q2; sq3[ll][b] = q3;
        sm[ll][b] = plp; sl[ll][b] = lbl;

        if (lbl != 4) {                         // CE (ignore_index = 4)
            float mx = fmaxf(fmaxf(av.x, av.y), fmaxf(av.z, av.w));
            float se = __expf(av.x - mx) + __expf(av.y - mx)
                     + __expf(av.z - mx) + __expf(av.w - mx);
            float lse = mx + __logf(se);
            float al = (lbl == 0) ? av.x : (lbl == 1) ? av.y
                     : (lbl == 2) ? av.z : av.w;
            ce = lse - al;
            valid = 1.f;
        }

        // R2: group of 4 = b bits 0,1 = t bits 4,5 (within the 64-lane wave)
        float nmc = (lbl != 4) ? 1.f : 0.f, altc = salt, ps = spalt;
        nmc  += __shfl_xor(nmc, 16);  nmc  += __shfl_xor(nmc, 32);
        altc += __shfl_xor(altc, 16); altc += __shfl_xor(altc, 32);
        ps   += __shfl_xor(ps, 16);   ps   += __shfl_xor(ps, 32);
        float af = altc / fmaxf(nmc, 1.f);
        float pred = 0.25f * ps;
        bool miss = (lbl == 4);
        float taf = miss ? 0.5f : af;
        bool edge = (taf == 0.f) || (taf == 1.f);
        float denom = fmaxf(taf * (1.f - taf), 0.01f);
        float d = pred - taf;
        float r2 = d * d / denom;
        if (edge || miss) r2 = 0.f;
        r2s -= r2;
        if (nmc > 0.f && r2 != 0.f) tv += 1.f;
    } else {
        // ---- w-table: row i = t2>>4, two cols per thread (coalesced float2)
        int t2 = t - 512;
        int i = t2 >> 4, jh = t2 & 15;
        float2 ye = *(const float2*)(yevo + i * 32 + 2 * jh);
        float e0 = __expf(-2.f * ye.x), e1 = __expf(-2.f * ye.y);
        float s = e0 + e1;
        s += __shfl_xor(s, 1);
        s += __shfl_xor(s, 2);
        s += __shfl_xor(s, 4);
        s += __shfl_xor(s, 8);                  // rowsum over 16 lanes x 2
        float inv = 1.f / (s + 1e-8f);
        w[i * 32 + 2 * jh]     = e0 * inv;
        w[i * 32 + 2 * jh + 1] = e1 * inv;
    }
    __syncthreads();

    // ---- phase 2: per-wave rotation; wave wv <-> l = l0+wv ----
    const int lane = t & 63;
    const int g = lane >> 5;                    // 0: d=1..8, 1: d=9..16
    const int b = lane & 31;                    // owned batch row
    const int wv = t >> 6;

    float q0 = sq0[wv][b], q1 = sq1[wv][b], q2 = sq2[wv][b], q3 = sq3[wv][b];
    float plp = sm[wv][b];
    int   lbl = sl[wv][b];

    float evo = 0.f;
    #pragma unroll
    for (int it = 0; it < 8; ++it) {
        int d = 1 + it + (g << 3);
        int jj = (b + d) & 31;
        int src = (lane & 32) | jj;
        float qj0 = __shfl(q0, src), qj1 = __shfl(q1, src);
        float qj2 = __shfl(q2, src), qj3 = __shfl(q3, src);
        float pj  = __shfl(plp, src);
        int   lj  = __shfl(lbl, src);
        float m0 = 0.5f * (q0 + qj0), m1 = 0.5f * (q1 + qj1);
        float m2 = 0.5f * (q2 + qj2), m3 = 0.5f * (q3 + qj3);
        float mlogm = m0 * __logf(m0) + m1 * __logf(m1)
                    + m2 * __logf(m2) + m3 * __logf(m3);
        float js = 0.5f * (plp + pj) - mlogm;
        bool act = (lbl == lj) && (lbl != 4) && !((d == 16) & (b >= 16));
        float wf = act ? (w[(b << 5) + jj] + w[(jj << 5) + b]) : 0.f;
        evo = fmaf(wf, js, evo);
    }

    // ---- wave reduction of 5 accumulators ----
    #pragma unroll
    for (int off = 32; off; off >>= 1) {
        ce += __shfl_xor(ce, off);   valid += __shfl_xor(valid, off);
        r2s += __shfl_xor(r2s, off); tv += __shfl_xor(tv, off);
        evo += __shfl_xor(evo, off);
    }
    if (lane == 0) {
        wred[wv][0] = ce; wred[wv][1] = valid; wred[wv][2] = r2s;
        wred[wv][3] = tv; wred[wv][4] = evo;
    }
    __syncthreads();

    // ---- cross-wave reduction (16 waves) by wave 0, lanes 0..15 ----
    if (t < 16) {
        float a0 = wred[t][0], a1 = wred[t][1], a2 = wred[t][2],
              a3 = wred[t][3], a4 = wred[t][4];
        #pragma unroll
        for (int off = 8; off; off >>= 1) {
            a0 += __shfl_xor(a0, off); a1 += __shfl_xor(a1, off);
            a2 += __shfl_xor(a2, off); a3 += __shfl_xor(a3, off);
            a4 += __shfl_xor(a4, off);
        }
        if (t == 0) {                   // [5][nblk] layout: k_final coalesced
            partials[0 * nblk + blk] = a0;
            partials[1 * nblk + blk] = a1;
            partials[2 * nblk + blk] = a2;
            partials[3 * nblk + blk] = a3;
            partials[4 * nblk + blk] = a4;
        }
    }
}

// Epilogue kernel: coalesced single-pass reduction of [5][nblk] partials.
__global__ __launch_bounds__(256) void k_final(const float* __restrict__ partials,
                                               float* __restrict__ out, int nblk) {
    __shared__ float wred[4][5];
    const int t = threadIdx.x;
    float s0 = 0.f, s1 = 0.f, s2 = 0.f, s3 = 0.f, s4 = 0.f;
    for (int idx = t; idx < nblk; idx += 256) {
        s0 += partials[0 * nblk + idx];
        s1 += partials[1 * nblk + idx];
        s2 += partials[2 * nblk + idx];
        s3 += partials[3 * nblk + idx];
        s4 += partials[4 * nblk + idx];
    }
    #pragma unroll
    for (int off = 32; off; off >>= 1) {
        s0 += __shfl_xor(s0, off); s1 += __shfl_xor(s1, off);
        s2 += __shfl_xor(s2, off); s3 += __shfl_xor(s3, off);
        s4 += __shfl_xor(s4, off);
    }
    const int wv = t >> 6;
    if ((t & 63) == 0) {
        wred[wv][0] = s0; wred[wv][1] = s1; wred[wv][2] = s2;
        wred[wv][3] = s3; wred[wv][4] = s4;
    }
    __syncthreads();
    if (t == 0) {
        float ce_sum = wred[0][0] + wred[1][0] + wred[2][0] + wred[3][0];
        float vcnt   = wred[0][1] + wred[1][1] + wred[2][1] + wred[3][1];
        float r2_sum = wred[0][2] + wred[1][2] + wred[2][2] + wred[3][2];
        float tvs    = wred[0][3] + wred[1][3] + wred[2][3] + wred[3][3];
        float evo_s  = wred[0][4] + wred[1][4] + wred[2][4] + wred[3][4];
        float ce_loss = (vcnt > 0.f) ? (ce_sum / fmaxf(vcnt, 1.f)) : ce_sum;
        float r2_loss = 0.1f * ((tvs > 0.f) ? (r2_sum / fmaxf(tvs, 1.f)) : r2_sum);
        float evo = 10.f * (evo_s / 32.f);
        if (!isfinite(evo)) evo = 0.f;
        out[0] = 1000.f * (ce_loss + r2_loss + evo);
    }
}

extern "C" void kernel_launch(void* const* d_in, const int* in_sizes, int n_in,
                              void* d_out, int out_size, void* d_ws, size_t ws_size,
                              hipStream_t stream) {
    const float* logits = (const float*)d_in[0];
    const float* prob   = (const float*)d_in[1];
    const float* y_true = (const float*)d_in[2];
    const float* yevo   = (const float*)d_in[3];
    float* out = (float*)d_out;

    const int L = in_sizes[0] / (B * C);   // 4096
    const int nblk = L / WPB;              // 256

    float* partials = (float*)d_ws;        // 5 * nblk floats

    k_main<<<nblk, NTHR, 0, stream>>>(logits, prob, y_true, yevo,
                                      partials, L, nblk);
    k_final<<<1, 256, 0, stream>>>(partials, out, nblk);
}